// Round 8
// baseline (525.142 us; speedup 1.0000x reference)
//
#include <hip/hip_runtime.h>
#include <cstdint>

#define BB 16
#define NN 65536
#define DD 32
#define KK 64
#define DELTA_V 0.5f
#define DELTA_D 1.5f
#define GRID 512          // 32 blocks per batch; 2 blocks/CU needed (cap >=4)
#define PPB 2048          // points per block
#define WPTS 512          // points per wave
#define NSTG 8            // 64-point stages per wave

typedef short bf16x8 __attribute__((ext_vector_type(8)));
typedef float f32x16 __attribute__((ext_vector_type(16)));

__device__ __forceinline__ short f2bf(float x) {
    union { float f; unsigned u; } v; v.f = x;
    const unsigned r = v.u + 0x7FFFu + ((v.u >> 16) & 1u);  // RNE
    return (short)(r >> 16);
}

__global__ __launch_bounds__(64) void k_init(int* bar) {
    if (threadIdx.x < 16) bar[threadIdx.x] = 0;
}

// device-scope grid barrier: release-add, acquire-spin, bounded failsafe
__device__ __forceinline__ void gbar(int* bar, int idx, int nb) {
    __syncthreads();
    if (threadIdx.x == 0) {
        __hip_atomic_fetch_add(&bar[idx], 1, __ATOMIC_RELEASE,
                               __HIP_MEMORY_SCOPE_AGENT);
        const long long t0 = clock64();
        while (__hip_atomic_load(&bar[idx], __ATOMIC_ACQUIRE,
                                 __HIP_MEMORY_SCOPE_AGENT) < nb) {
            __builtin_amdgcn_s_sleep(4);
            if (clock64() - t0 > (long long)4e8) break;   // fail loud, not hung
        }
    }
    __syncthreads();
}

__global__ __launch_bounds__(256, 2) void k_fused(
    const float* __restrict__ emb, const int* __restrict__ ids,
    const int* __restrict__ mask, float* parts, float* pcnt, float* mu,
    float* varpart, float* aux, int* bar, float* __restrict__ out)
{
    __shared__ float tb[4][64][36];   // 36.9 KB multi-purpose
    __shared__ float lc2[4][KK];
    __shared__ float red[4];
    __shared__ float sfin[4][BB];
    const int tid  = threadIdx.x;
    const int w    = tid >> 6, lane = tid & 63;
    const int half = lane >> 5, d32 = lane & 31;
    const int pl   = lane >> 3, pc = lane & 7;
    const int gblk = blockIdx.x;
    const int b    = gblk >> 5;
    const size_t pw = (size_t)b * NN + (size_t)(gblk & 31) * PPB + (size_t)w * WPTS;

    // ======== phase 1: one-hot MFMA partial segment-sums ========
    {
        f32x16 acc0 = {}, acc1 = {};
        int c0 = 0, c1 = 0;
        const int m0 = d32, m1 = d32 + 32;
        float (*T)[36] = tb[w];
        const float4* epb  = (const float4*)(emb + pw * DD);
        const int*    idsb = ids + pw;
        const int*    mskb = mask + pw;

        float4 r[8]; int idr, mkr;
#pragma unroll
        for (int i = 0; i < 8; ++i) r[i] = epb[i * 64 + lane];
        idr = idsb[lane]; mkr = mskb[lane];

#pragma unroll
        for (int s = 0; s < NSTG; ++s) {
            float4 r2[8]; int idr2 = 0, mkr2 = 0;
            if (s < NSTG - 1) {                  // prefetch next stage
                const float4* ep4 = epb + (s + 1) * 512;
#pragma unroll
                for (int i = 0; i < 8; ++i) r2[i] = ep4[i * 64 + lane];
                idr2 = idsb[(s + 1) * 64 + lane];
                mkr2 = mskb[(s + 1) * 64 + lane];
            }
            const int vid = (mkr != 0 && (unsigned)idr < KK) ? idr : -1;
#pragma unroll
            for (int i = 0; i < 8; ++i)
                *(float4*)&T[i * 8 + pl][4 * pc] = r[i];
#pragma unroll
            for (int q = 0; q < 4; ++q) {
                bf16x8 bfB, a0, a1;
#pragma unroll
                for (int e = 0; e < 8; ++e) {
                    bfB[e] = f2bf(T[q * 16 + 8 * half + e][d32]);
                    const int s_lo = __builtin_amdgcn_readlane(vid, q * 16 + e);
                    const int s_hi = __builtin_amdgcn_readlane(vid, q * 16 + 8 + e);
                    const int sel  = half ? s_hi : s_lo;
                    const bool h0 = (sel == m0), h1 = (sel == m1);
                    a0[e] = h0 ? (short)0x3F80 : (short)0;   // bf16 1.0
                    a1[e] = h1 ? (short)0x3F80 : (short)0;
                    c0 += h0 ? 1 : 0;
                    c1 += h1 ? 1 : 0;
                }
                acc0 = __builtin_amdgcn_mfma_f32_32x32x16_bf16(a0, bfB, acc0, 0, 0, 0);
                acc1 = __builtin_amdgcn_mfma_f32_32x32x16_bf16(a1, bfB, acc1, 0, 0, 0);
            }
            if (s < NSTG - 1) {
#pragma unroll
                for (int i = 0; i < 8; ++i) r[i] = r2[i];
                idr = idr2; mkr = mkr2;
            }
        }
        // park C fragments (verified C/D layout) + counts, block-reduce
#pragma unroll
        for (int rr = 0; rr < 16; ++rr) {
            const int mrow = (rr & 3) + 8 * (rr >> 2) + 4 * half;
            T[mrow][d32]      = acc0[rr];
            T[32 + mrow][d32] = acc1[rr];
        }
        c0 += __shfl_down(c0, 32);
        c1 += __shfl_down(c1, 32);
        if (lane < 32) { lc2[w][lane] = (float)c0; lc2[w][lane + 32] = (float)c1; }
        __syncthreads();

        float* pb = parts + (size_t)gblk * 2048;
        for (int i = tid; i < 2048; i += 256) {
            const int row = i >> 5, col = i & 31;
            pb[i] = tb[0][row][col] + tb[1][row][col]
                  + tb[2][row][col] + tb[3][row][col];
        }
        if (tid < KK)
            pcnt[(size_t)gblk * KK + tid] =
                lc2[0][tid] + lc2[1][tid] + lc2[2][tid] + lc2[3][tid];
    }

    gbar(bar, 0, GRID);

    // ======== phase 1.5: 16 reducer blocks -> mu / reg / push ========
    if (gblk < BB) {
        const int rb = gblk;
        float (*lm)[36] = tb[0];
        float* lcnt = lc2[0];
        if (tid < KK) {
            float s = 0.f;
            for (int j = 0; j < 32; ++j)
                s += pcnt[((size_t)(rb * 32 + j)) * KK + tid];
            lcnt[tid] = s;
            mu[(size_t)rb * KK * 36 + tid * 36 + 32] = s;
            mu[(size_t)rb * KK * 36 + tid * 36 + 33] = 1.f / fmaxf(s, 1.f);
        }
        __syncthreads();
        for (int e = tid; e < 2048; e += 256) {
            float s = 0.f;
            for (int j = 0; j < 32; ++j)
                s += parts[((size_t)(rb * 32 + j)) * 2048 + e];
            const int k = e >> 5, d = e & 31;
            const float m = s / fmaxf(lcnt[k], 1.f);
            lm[k][d] = m;
            mu[(size_t)rb * KK * 36 + k * 36 + d] = m;
        }
        __syncthreads();

        float ninst = 0.f;
        if (tid < KK) {
            const float c = lcnt[tid];
            const float pres = (c > 0.f) ? 1.f : 0.f;
            float sq = 0.f;
#pragma unroll
            for (int d = 0; d < DD; ++d) { const float m = lm[tid][d]; sq = fmaf(m, m, sq); }
            float nm = ((sq > 0.f) ? sqrtf(sq) : 0.f) * pres;
            float pn = pres;
            for (int off = 32; off; off >>= 1) {
                pn += __shfl_down(pn, off);
                nm += __shfl_down(nm, off);
            }
            if (tid == 0) {
                ninst = pn;
                aux[rb]      = nm / fmaxf(pn, 1.f);   // reg_b
                aux[32 + rb] = pn;                    // num_inst
            }
        }
        float acc = 0.f;
        for (int idx = tid; idx < KK * KK; idx += 256) {
            const int i = idx >> 6, j = idx & 63;
            if (i < j && lcnt[i] > 0.f && lcnt[j] > 0.f) {
                float dsq = 0.f;
#pragma unroll
                for (int d = 0; d < DD; ++d) {
                    const float df = lm[i][d] - lm[j][d];
                    dsq = fmaf(df, df, dsq);
                }
                const float pd = (dsq > 0.f) ? sqrtf(dsq) : 0.f;
                const float pen = fmaxf(2.f * DELTA_D - pd, 0.f);
                acc = fmaf(pen, pen, acc);
            }
        }
        for (int off = 32; off; off >>= 1) acc += __shfl_down(acc, off);
        if ((tid & 63) == 0) red[tid >> 6] = acc;
        __syncthreads();
        if (tid == 0) {
            const float tot = red[0] + red[1] + red[2] + red[3];
            const float np = ninst * (ninst - 1.f) * 0.5f;
            aux[16 + rb] = tot / fmaxf(np, 1.f);      // dist_b
        }
    }

    gbar(bar, 1, GRID);

    // ======== phase 2: pull pass (emb re-read, L3-hot) ========
    {
        float (*smu)[36] = tb[0];
        const float* mub = mu + (size_t)b * KK * 36;
        for (int i = tid; i < KK * 36; i += 256) ((float*)smu)[i] = mub[i];
        __syncthreads();

        const float4* epb  = (const float4*)(emb + pw * DD);
        const int*    idsb = ids + pw;
        const int*    mskb = mask + pw;
        float accv = 0.f;
        for (int t = 0; t < 8; ++t) {
            const int idr = idsb[t * 64 + lane];
            const int mkr = mskb[t * 64 + lane];
            const int vid = (mkr != 0 && (unsigned)idr < KK) ? idr : -1;
            float4 x[8];
#pragma unroll
            for (int g = 0; g < 8; ++g) x[g] = epb[t * 512 + g * 64 + lane];
#pragma unroll
            for (int g = 0; g < 8; ++g) {
                const int sid = __shfl(vid, g * 8 + pl);
                const int row = (sid >= 0) ? sid : 0;
                const float4 m4 = *(const float4*)&smu[row][4 * pc];
                float a = x[g].x - m4.x; float dsq = a * a;
                a = x[g].y - m4.y; dsq = fmaf(a, a, dsq);
                a = x[g].z - m4.z; dsq = fmaf(a, a, dsq);
                a = x[g].w - m4.w; dsq = fmaf(a, a, dsq);
                dsq += __shfl_xor(dsq, 1);
                dsq += __shfl_xor(dsq, 2);
                dsq += __shfl_xor(dsq, 4);
                if (pc == 0 && sid >= 0) {
                    const float dist = (dsq > 0.f) ? sqrtf(dsq) : 0.f;
                    float pen = fmaxf(dist - DELTA_V, 0.f);
                    accv = fmaf(pen * pen, smu[row][33], accv);
                }
            }
        }
        for (int off = 32; off; off >>= 1) accv += __shfl_down(accv, off);
        if (lane == 0) red[w] = accv;
        __syncthreads();
        if (tid == 0) varpart[gblk] = red[0] + red[1] + red[2] + red[3];
    }

    gbar(bar, 2, GRID);

    // ======== phase 3: block 0 combines ========
    if (gblk == 0) {
        if (tid < BB) {
            float vs = 0.f;
            for (int j = 0; j < 32; ++j) vs += varpart[tid * 32 + j];
            const float ni = aux[32 + tid];
            sfin[0][tid] = vs / fmaxf(ni, 1.f);       // var_b
            sfin[1][tid] = (ni >= 2.f) ? 1.f : 0.f;   // valid
            sfin[2][tid] = aux[tid];                  // reg_b
            sfin[3][tid] = aux[16 + tid];             // dist_b
        }
        __syncthreads();
        if (tid == 0) {
            float denom = 0.f, v = 0.f, d = 0.f, r = 0.f;
            for (int bb = 0; bb < BB; ++bb) {
                const float vb = sfin[1][bb];
                denom += vb;
                v += sfin[0][bb] * vb;
                d += sfin[3][bb] * vb;
                r += sfin[2][bb] * vb;
            }
            denom = fmaxf(denom, 1.f);
            v /= denom; d /= denom; r /= denom;
            out[0] = v + d + 0.001f * r;   // ALPHA=BETA=1, GAMMA=0.001
            out[1] = v;
            out[2] = d;
            out[3] = r;
        }
    }
}

// ---------------------------------------------------------------------------
extern "C" void kernel_launch(void* const* d_in, const int* in_sizes, int n_in,
                              void* d_out, int out_size, void* d_ws, size_t ws_size,
                              hipStream_t stream)
{
    const float* emb  = (const float*)d_in[0];
    const int*   ids  = (const int*)d_in[1];
    const int*   mask = (const int*)d_in[2];   // bool widened to int32

    float* ws      = (float*)d_ws;
    int*   bar     = (int*)ws;                              // 16 ints
    float* parts   = ws + 64;                               // 512*2048
    float* pcnt    = parts + (size_t)GRID * 2048;           // 512*64
    float* mu      = pcnt + (size_t)GRID * KK;              // 16*64*36
    float* varpart = mu + (size_t)BB * KK * 36;             // 512
    float* aux     = varpart + GRID;                        // 48

    k_init<<<1, 64, 0, stream>>>(bar);
    k_fused<<<GRID, 256, 0, stream>>>(emb, ids, mask, parts, pcnt, mu,
                                      varpart, aux, bar, (float*)d_out);
}

// Round 9
// 100.974 us; speedup vs baseline: 5.2008x; 5.2008x over previous
//
#include <hip/hip_runtime.h>
#include <cstdint>

#define BB 16
#define NN 65536
#define DD 32
#define KK 64
#define DELTA_V 0.5f
#define DELTA_D 1.5f
#define GRID 512          // 32 blocks/batch; 2 blocks/CU needed (LDS cap = 4)
#define PPB 2048          // points per block
#define WPTS 512          // points per wave
#define NSTG 8            // 64-point stages per wave

typedef short bf16x8 __attribute__((ext_vector_type(8)));
typedef float f32x16 __attribute__((ext_vector_type(16)));

__device__ __forceinline__ short f2bf(float x) {
    union { float f; unsigned u; } v; v.f = x;
    const unsigned r = v.u + 0x7FFFu + ((v.u >> 16) & 1u);  // RNE
    return (short)(r >> 16);
}

// --- coherent flag ops: RELAXED RMW polls (no per-poll cache maintenance),
// --- single RELEASE on arrival / single ACQUIRE on spin exit.
__device__ __forceinline__ int fpoll(int* p) {
    return __hip_atomic_fetch_add(p, 0, __ATOMIC_RELAXED, __HIP_MEMORY_SCOPE_AGENT);
}
__device__ __forceinline__ void arrive(int* p) {
    __hip_atomic_fetch_add(p, 1, __ATOMIC_RELEASE, __HIP_MEMORY_SCOPE_AGENT);
}
__device__ __forceinline__ void spinge(int* p, int tgt) {
    const long long t0 = clock64();
    while (fpoll(p) < tgt) {
        __builtin_amdgcn_s_sleep(8);
        if (clock64() - t0 > (long long)2e8) break;   // fail loud, not hung
    }
    (void)__hip_atomic_load(p, __ATOMIC_ACQUIRE, __HIP_MEMORY_SCOPE_AGENT);
}

__global__ __launch_bounds__(64) void k_init(int* bar) {
    for (int j = threadIdx.x; j < 2048; j += 64) bar[j] = 0;
}

// flags (128B-separated): done1[b]=bar[b*32]; auxdone=bar[512]; done2=bar[544]

__global__ __launch_bounds__(256, 2) void k_fused(
    const float* __restrict__ emb, const int* __restrict__ ids,
    const int* __restrict__ mask, float* parts, float* pcnt,
    float* varpart, float* aux, int* bar, float* __restrict__ out)
{
    __shared__ float tb[4][64][36];   // 36.9 KB multi-purpose
    __shared__ float lc2[4][KK];
    __shared__ float red[4];
    __shared__ float sf[4][BB];
    __shared__ int s_last;
    const int tid  = threadIdx.x;
    const int w    = tid >> 6, lane = tid & 63;
    const int half = lane >> 5, d32 = lane & 31;
    const int pl   = lane >> 3, pc = lane & 7;
    const int gblk = blockIdx.x;
    const int b    = gblk >> 5;
    const size_t pw = (size_t)b * NN + (size_t)(gblk & 31) * PPB + (size_t)w * WPTS;

    // ======== phase 1: one-hot MFMA partial segment-sums (round-8 proven) ====
    {
        f32x16 acc0 = {}, acc1 = {};
        int c0 = 0, c1 = 0;
        const int m0 = d32, m1 = d32 + 32;
        float (*T)[36] = tb[w];
        const float4* epb  = (const float4*)(emb + pw * DD);
        const int*    idsb = ids + pw;
        const int*    mskb = mask + pw;

        float4 r[8]; int idr, mkr;
#pragma unroll
        for (int i = 0; i < 8; ++i) r[i] = epb[i * 64 + lane];
        idr = idsb[lane]; mkr = mskb[lane];

#pragma unroll
        for (int s = 0; s < NSTG; ++s) {
            float4 r2[8]; int idr2 = 0, mkr2 = 0;
            if (s < NSTG - 1) {                  // prefetch next stage
                const float4* ep4 = epb + (s + 1) * 512;
#pragma unroll
                for (int i = 0; i < 8; ++i) r2[i] = ep4[i * 64 + lane];
                idr2 = idsb[(s + 1) * 64 + lane];
                mkr2 = mskb[(s + 1) * 64 + lane];
            }
            const int vid = (mkr != 0 && (unsigned)idr < KK) ? idr : -1;
#pragma unroll
            for (int i = 0; i < 8; ++i)
                *(float4*)&T[i * 8 + pl][4 * pc] = r[i];
#pragma unroll
            for (int q = 0; q < 4; ++q) {
                bf16x8 bfB, a0, a1;
#pragma unroll
                for (int e = 0; e < 8; ++e) {
                    bfB[e] = f2bf(T[q * 16 + 8 * half + e][d32]);
                    const int s_lo = __builtin_amdgcn_readlane(vid, q * 16 + e);
                    const int s_hi = __builtin_amdgcn_readlane(vid, q * 16 + 8 + e);
                    const int sel  = half ? s_hi : s_lo;
                    const bool h0 = (sel == m0), h1 = (sel == m1);
                    a0[e] = h0 ? (short)0x3F80 : (short)0;   // bf16 1.0
                    a1[e] = h1 ? (short)0x3F80 : (short)0;
                    c0 += h0 ? 1 : 0;
                    c1 += h1 ? 1 : 0;
                }
                acc0 = __builtin_amdgcn_mfma_f32_32x32x16_bf16(a0, bfB, acc0, 0, 0, 0);
                acc1 = __builtin_amdgcn_mfma_f32_32x32x16_bf16(a1, bfB, acc1, 0, 0, 0);
            }
            if (s < NSTG - 1) {
#pragma unroll
                for (int i = 0; i < 8; ++i) r[i] = r2[i];
                idr = idr2; mkr = mkr2;
            }
        }
#pragma unroll
        for (int rr = 0; rr < 16; ++rr) {
            const int mrow = (rr & 3) + 8 * (rr >> 2) + 4 * half;
            T[mrow][d32]      = acc0[rr];
            T[32 + mrow][d32] = acc1[rr];
        }
        c0 += __shfl_down(c0, 32);
        c1 += __shfl_down(c1, 32);
        if (lane < 32) { lc2[w][lane] = (float)c0; lc2[w][lane + 32] = (float)c1; }
        __syncthreads();

        float* pb = parts + (size_t)gblk * 2048;
        for (int i = tid; i < 2048; i += 256) {
            const int row = i >> 5, col = i & 31;
            pb[i] = tb[0][row][col] + tb[1][row][col]
                  + tb[2][row][col] + tb[3][row][col];
        }
        if (tid < KK)
            pcnt[(size_t)gblk * KK + tid] =
                lc2[0][tid] + lc2[1][tid] + lc2[2][tid] + lc2[3][tid];
    }
    __syncthreads();                  // drains each wave's stores (vmcnt)

    // ======== per-batch barrier (cheap polls) ========
    if (tid == 0) {
        arrive(&bar[b * 32]);
        spinge(&bar[b * 32], 32);
    }
    __syncthreads();

    // ======== every block redundantly builds its batch's means in LDS ====
    float (*smu)[36] = tb[0];
    if (tid < KK) {
        float s = 0.f;
        const float* pc0 = pcnt + (size_t)b * 32 * KK + tid;
        for (int j = 0; j < 32; ++j) s += pc0[j * KK];
        smu[tid][32] = s;
        smu[tid][33] = 1.f / fmaxf(s, 1.f);
    }
    __syncthreads();
    for (int e = tid; e < 2048; e += 256) {
        float s = 0.f;
        const float* pp = parts + (size_t)b * 32 * 2048 + e;
        for (int j = 0; j < 32; ++j) s += pp[j * 2048];
        smu[e >> 5][e & 31] = s * smu[e >> 5][33];
    }
    __syncthreads();

    // ======== designated block per batch: reg + push losses ========
    if ((gblk & 31) == 0) {
        float ninst = 0.f;
        if (tid < KK) {
            const float c = smu[tid][32];
            const float pres = (c > 0.f) ? 1.f : 0.f;
            float sq = 0.f;
#pragma unroll
            for (int d = 0; d < DD; ++d) { const float m = smu[tid][d]; sq = fmaf(m, m, sq); }
            float nm = ((sq > 0.f) ? sqrtf(sq) : 0.f) * pres;
            float pn = pres;
            for (int off = 32; off; off >>= 1) {
                pn += __shfl_down(pn, off);
                nm += __shfl_down(nm, off);
            }
            if (tid == 0) {
                ninst = pn;
                aux[b]      = nm / fmaxf(pn, 1.f);   // reg_b
                aux[32 + b] = pn;                    // num_inst
            }
        }
        float acc = 0.f;
        for (int idx = tid; idx < KK * KK; idx += 256) {
            const int i = idx >> 6, j = idx & 63;
            if (i < j && smu[i][32] > 0.f && smu[j][32] > 0.f) {
                float dsq = 0.f;
#pragma unroll
                for (int d = 0; d < DD; ++d) {
                    const float df = smu[i][d] - smu[j][d];
                    dsq = fmaf(df, df, dsq);
                }
                const float pd = (dsq > 0.f) ? sqrtf(dsq) : 0.f;
                const float pen = fmaxf(2.f * DELTA_D - pd, 0.f);
                acc = fmaf(pen, pen, acc);
            }
        }
        for (int off = 32; off; off >>= 1) acc += __shfl_down(acc, off);
        if ((tid & 63) == 0) red[tid >> 6] = acc;
        __syncthreads();
        if (tid == 0) {
            const float tot = red[0] + red[1] + red[2] + red[3];
            const float np = ninst * (ninst - 1.f) * 0.5f;
            aux[16 + b] = tot / fmaxf(np, 1.f);      // dist_b
            arrive(&bar[512]);                       // auxdone
        }
        __syncthreads();
    }

    // ======== pull pass (emb re-read, L3-hot; smu already in LDS) ========
    {
        const float4* epb  = (const float4*)(emb + pw * DD);
        const int*    idsb = ids + pw;
        const int*    mskb = mask + pw;
        float accv = 0.f;
        for (int t = 0; t < 8; ++t) {
            const int idr = idsb[t * 64 + lane];
            const int mkr = mskb[t * 64 + lane];
            const int vid = (mkr != 0 && (unsigned)idr < KK) ? idr : -1;
            float4 x[8];
#pragma unroll
            for (int g = 0; g < 8; ++g) x[g] = epb[t * 512 + g * 64 + lane];
#pragma unroll
            for (int g = 0; g < 8; ++g) {
                const int sid = __shfl(vid, g * 8 + pl);
                const int row = (sid >= 0) ? sid : 0;
                const float4 m4 = *(const float4*)&smu[row][4 * pc];
                float a = x[g].x - m4.x; float dsq = a * a;
                a = x[g].y - m4.y; dsq = fmaf(a, a, dsq);
                a = x[g].z - m4.z; dsq = fmaf(a, a, dsq);
                a = x[g].w - m4.w; dsq = fmaf(a, a, dsq);
                dsq += __shfl_xor(dsq, 1);
                dsq += __shfl_xor(dsq, 2);
                dsq += __shfl_xor(dsq, 4);
                if (pc == 0 && sid >= 0) {
                    const float dist = (dsq > 0.f) ? sqrtf(dsq) : 0.f;
                    float pen = fmaxf(dist - DELTA_V, 0.f);
                    accv = fmaf(pen * pen, smu[row][33], accv);
                }
            }
        }
        for (int off = 32; off; off >>= 1) accv += __shfl_down(accv, off);
        if (lane == 0) red[w] = accv;
        __syncthreads();
        if (tid == 0) varpart[gblk] = red[0] + red[1] + red[2] + red[3];
    }

    // ======== done-ticket: last-arriving block combines ========
    if (tid == 0) {
        const int ret = __hip_atomic_fetch_add(&bar[544], 1, __ATOMIC_RELEASE,
                                               __HIP_MEMORY_SCOPE_AGENT);
        s_last = (ret == GRID - 1) ? 1 : 0;
        if (s_last) spinge(&bar[512], BB);   // auxdone (acquire on exit)
    }
    __syncthreads();
    if (s_last) {
        if (tid < BB) {
            float vs = 0.f;
            for (int j = 0; j < 32; ++j) vs += varpart[tid * 32 + j];
            const float ni = aux[32 + tid];
            sf[0][tid] = vs / fmaxf(ni, 1.f);
            sf[1][tid] = (ni >= 2.f) ? 1.f : 0.f;
            sf[2][tid] = aux[tid];
            sf[3][tid] = aux[16 + tid];
        }
        __syncthreads();
        if (tid == 0) {
            float denom = 0.f, v = 0.f, d = 0.f, r = 0.f;
            for (int bb = 0; bb < BB; ++bb) {
                const float vb = sf[1][bb];
                denom += vb;
                v += sf[0][bb] * vb;
                d += sf[3][bb] * vb;
                r += sf[2][bb] * vb;
            }
            denom = fmaxf(denom, 1.f);
            v /= denom; d /= denom; r /= denom;
            out[0] = v + d + 0.001f * r;   // ALPHA=BETA=1, GAMMA=0.001
            out[1] = v;
            out[2] = d;
            out[3] = r;
        }
    }
}

// ---------------------------------------------------------------------------
extern "C" void kernel_launch(void* const* d_in, const int* in_sizes, int n_in,
                              void* d_out, int out_size, void* d_ws, size_t ws_size,
                              hipStream_t stream)
{
    const float* emb  = (const float*)d_in[0];
    const int*   ids  = (const int*)d_in[1];
    const int*   mask = (const int*)d_in[2];   // bool widened to int32

    float* ws      = (float*)d_ws;
    int*   bar     = (int*)ws;                              // 2048 ints
    float* parts   = ws + 2048;                             // 512*2048
    float* pcnt    = parts + (size_t)GRID * 2048;           // 512*64
    float* varpart = pcnt + (size_t)GRID * KK;              // 512
    float* aux     = varpart + GRID;                        // 48

    k_init<<<1, 64, 0, stream>>>(bar);
    k_fused<<<GRID, 256, 0, stream>>>(emb, ids, mask, parts, pcnt,
                                      varpart, aux, bar, (float*)d_out);
}